// Round 14
// baseline (304.580 us; speedup 1.0000x reference)
//
#include <hip/hip_runtime.h>

#define N_NODES 50000
#define N_EDGES 600000
#define E_PAD_MAX (N_EDGES + N_NODES * 7)   // padded edge capacity

using bf16x8 = __attribute__((ext_vector_type(8))) short;
using f32x4  = __attribute__((ext_vector_type(4))) float;
typedef unsigned int uint32_tt;

__device__ __forceinline__ unsigned short f2bf(float f) {
    union { float f; unsigned int u; } v; v.f = f;
    unsigned int u = v.u;
    return (unsigned short)((u + 0x7fffu + ((u >> 16) & 1u)) >> 16);  // RNE
}
__device__ __forceinline__ float bf2f(unsigned int h16) {
    union { unsigned int u; float f; } v; v.u = h16 << 16;
    return v.f;
}

// ---------------- merged prep (runs FIRST, depends on nothing) ---------------
__global__ void prep_kernel(
    const float* __restrict__ x0, unsigned short* __restrict__ xb,
    const float* __restrict__ wr0, const float* __restrict__ wi0,
    const float* __restrict__ lw0, unsigned short* __restrict__ BT0,
    const float* __restrict__ wr1, const float* __restrict__ wi1,
    const float* __restrict__ lw1, unsigned short* __restrict__ BT1,
    const float* __restrict__ wr2, const float* __restrict__ wi2,
    const float* __restrict__ lw2, unsigned short* __restrict__ BT2,
    int* __restrict__ cnt, uint2* __restrict__ edat, int n) {
    int tid = blockIdx.x * 256 + threadIdx.x;
    int nth = gridDim.x * 256;
    for (int i = tid; i < N_NODES; i += nth) cnt[i] = 0;
    uint2 z; z.x = 0u; z.y = 0u;
    for (int i = tid; i < E_PAD_MAX; i += nth) edat[i] = z;

    int i = tid;
    int nconv = n * 96;
    if (i < nconv) {
        int r = i / 96, c = i - r * 96;
        xb[i] = (c < 75) ? f2bf(x0[r * 75 + c]) : (unsigned short)0;
        return;
    }
    i -= nconv;
    if (i < 128 * 288) {   // BT0: CIN=75 CINP=96 COUT=128
        int nn = i / 288, k = i - nn * 288;
        int part = k / 96, kk = k - part * 96;
        float v = 0.f;
        if (kk < 75) {
            if (part == 0)      v = wr0[kk * 128 + nn];
            else if (part == 1) v = -wi0[kk * 128 + nn];
            else                v = lw0[nn * 75 + kk];
        }
        BT0[i] = f2bf(v);
        return;
    }
    i -= 128 * 288;
    if (i < 128 * 384) {   // BT1: CIN=CINP=128 COUT=128
        int nn = i / 384, k = i - nn * 384;
        int part = k >> 7, kk = k & 127;
        float v;
        if (part == 0)      v = wr1[kk * 128 + nn];
        else if (part == 1) v = -wi1[kk * 128 + nn];
        else                v = lw1[nn * 128 + kk];
        BT1[i] = f2bf(v);
        return;
    }
    i -= 128 * 384;
    if (i < 96 * 128) {    // BT2 (Y-projection): [96 rows][128 k] = [wr2|-wi2|lw2^T]
        int nn = i >> 7, k = i & 127;
        float v;
        if (nn < 32)      v = wr2[k * 32 + nn];
        else if (nn < 64) v = -wi2[k * 32 + (nn - 32)];
        else              v = lw2[(nn - 64) * 128 + k];
        BT2[i] = f2bf(v);
    }
}

// ---------------- CSR build (degrees padded to multiple of 8) ----------------

__global__ void hist_kernel(const int* __restrict__ ei, int* __restrict__ cnt,
                            int* __restrict__ rank, int E) {
    int e = blockIdx.x * 256 + threadIdx.x;
    if (e < E) rank[e] = atomicAdd(&cnt[ei[E + e]], 1);
}

__global__ void scan1(const int* __restrict__ deg, int* __restrict__ out,
                      int* __restrict__ bsum, int n) {
    __shared__ int s[256];
    int t = threadIdx.x;
    int base = blockIdx.x * 1024 + t * 4;
    int v0 = (base + 0 < n) ? ((deg[base + 0] + 7) & ~7) : 0;
    int v1 = (base + 1 < n) ? ((deg[base + 1] + 7) & ~7) : 0;
    int v2 = (base + 2 < n) ? ((deg[base + 2] + 7) & ~7) : 0;
    int v3 = (base + 3 < n) ? ((deg[base + 3] + 7) & ~7) : 0;
    int tsum = v0 + v1 + v2 + v3;
    s[t] = tsum;
    __syncthreads();
    for (int off = 1; off < 256; off <<= 1) {
        int tmp = (t >= off) ? s[t - off] : 0;
        __syncthreads();
        s[t] += tmp;
        __syncthreads();
    }
    int excl = s[t] - tsum;
    if (base + 0 < n) out[base + 0] = excl;
    if (base + 1 < n) out[base + 1] = excl + v0;
    if (base + 2 < n) out[base + 2] = excl + v0 + v1;
    if (base + 3 < n) out[base + 3] = excl + v0 + v1 + v2;
    if (t == 255) bsum[blockIdx.x] = s[255];
}

// scan3 with scan2 folded in (thread 0 sums <=49 L2-hot block totals)
__global__ void scan3(int* __restrict__ off, const int* __restrict__ bsum,
                      int n, int nb) {
    __shared__ int sp;
    int b = blockIdx.x, t = threadIdx.x;
    int seg = b >> 2;
    if (t == 0) {
        int acc = 0;
        for (int k = 0; k < seg; ++k) acc += bsum[k];
        sp = acc;
    }
    __syncthreads();
    int i = b * 256 + t;
    if (i < n) off[i] += sp;
    if (i == n) {
        int tot = sp;
        for (int k = seg; k < nb; ++k) tot += bsum[k];
        off[n] = tot;
    }
}

// atomic-free scatter: p = off[d] + rank[e]
__global__ void scatter_kernel(const int* __restrict__ ei, const float* __restrict__ w,
                               const float* __restrict__ sim, const int* __restrict__ off,
                               const int* __restrict__ rank, uint2* __restrict__ edat,
                               int E) {
    int e = blockIdx.x * 256 + threadIdx.x;
    if (e >= E) return;
    int s = ei[e], d = ei[E + e];
    int p = off[d] + rank[e];
    float wt = w[e];
    uint2 m;
    m.x = (unsigned)s;
    m.y = (uint32_tt)f2bf(wt * sim[2 * e]) |
          ((uint32_tt)f2bf(wt * sim[2 * e + 1]) << 16);
    edat[p] = m;
}

// ---------------- aggregation: TWO waves per node (wave-level range split) ---
// Each wave owns a uniform sub-range of the node's edges -> metadata stays
// readfirstlane-scalarized with zero lane-dependent selects (the R6/R12
// demotion trigger). Halves the serial batch chain per node. Partials combine
// via 2KB LDS + one __syncthreads. Block = 4 waves = 2 nodes; N even.
template <int CU2>  // uint32s per feature row (= CINP/2)
__global__ __launch_bounds__(256) void agg_bf16(
    const uint32_tt* __restrict__ x, const int* __restrict__ off,
    const uint2* __restrict__ edat, uint32_tt* __restrict__ aggR,
    uint32_tt* __restrict__ aggI, int n) {
    __shared__ float part[2][4][64];
    int wave = threadIdx.x >> 6;
    int lane = threadIdx.x & 63;
    int pair = wave >> 1, half = wave & 1;
    int node = __builtin_amdgcn_readfirstlane(blockIdx.x * 2 + pair);
    int lc = (CU2 == 64) ? lane : (lane < CU2 ? lane : CU2 - 1);  // clamped lane
    float arl = 0.f, arh = 0.f, ail = 0.f, aih = 0.f;
    int eb = __builtin_amdgcn_readfirstlane(off[node]);
    int ee = __builtin_amdgcn_readfirstlane(off[node + 1]);
    int nbat = (ee - eb) >> 3;
    int b0 = (nbat + 1) >> 1;            // first-half batch count
    int e0 = half ? eb + b0 * 8 : eb;
    int e1 = half ? ee : eb + b0 * 8;

    if (e0 < e1) {
        uint2 mn[8];
        int sc[8]; float crc[8], cic[8];
        uint32_tt wc[8];
        {
            uint2 m0[8];
#pragma unroll
            for (int j = 0; j < 8; ++j) m0[j] = edat[e0 + j];
#pragma unroll
            for (int j = 0; j < 8; ++j) {
                sc[j] = __builtin_amdgcn_readfirstlane((int)m0[j].x);
                int pk = __builtin_amdgcn_readfirstlane((int)m0[j].y);
                crc[j] = bf2f((unsigned)pk & 0xffffu);
                cic[j] = bf2f((unsigned)pk >> 16);
            }
            int nb = (e0 + 8 < e1) ? e0 + 8 : e0;
#pragma unroll
            for (int j = 0; j < 8; ++j) mn[j] = edat[nb + j];
#pragma unroll
            for (int j = 0; j < 8; ++j) wc[j] = x[(size_t)sc[j] * CU2 + lc];
        }
        for (int e = e0;; e += 8) {
            bool more = (e + 8 < e1);      // wave-uniform
            int sn[8]; float crn[8], cin_[8]; uint32_tt wn[8];
            if (more) {
#pragma unroll
                for (int j = 0; j < 8; ++j) {
                    sn[j] = __builtin_amdgcn_readfirstlane((int)mn[j].x);
                    int pk = __builtin_amdgcn_readfirstlane((int)mn[j].y);
                    crn[j] = bf2f((unsigned)pk & 0xffffu);
                    cin_[j] = bf2f((unsigned)pk >> 16);
                }
                int nb = (e + 16 < e1) ? e + 16 : e + 8;
#pragma unroll
                for (int j = 0; j < 8; ++j) mn[j] = edat[nb + j];
#pragma unroll
                for (int j = 0; j < 8; ++j) wn[j] = x[(size_t)sn[j] * CU2 + lc];
            }
#pragma unroll
            for (int j = 0; j < 8; ++j) {
                float lo = bf2f(wc[j] & 0xffffu), hi = bf2f(wc[j] >> 16);
                arl += crc[j] * lo; arh += crc[j] * hi;
                ail += cic[j] * lo; aih += cic[j] * hi;
            }
            if (!more) break;
#pragma unroll
            for (int j = 0; j < 8; ++j) {
                sc[j] = sn[j]; crc[j] = crn[j]; cic[j] = cin_[j]; wc[j] = wn[j];
            }
        }
    }
    if (half) {
        part[pair][0][lane] = arl; part[pair][1][lane] = arh;
        part[pair][2][lane] = ail; part[pair][3][lane] = aih;
    }
    __syncthreads();
    if (!half && lane < CU2) {
        arl += part[pair][0][lane]; arh += part[pair][1][lane];
        ail += part[pair][2][lane]; aih += part[pair][3][lane];
        aggR[(size_t)node * CU2 + lane] = (uint32_tt)f2bf(arl) | ((uint32_tt)f2bf(arh) << 16);
        aggI[(size_t)node * CU2 + lane] = (uint32_tt)f2bf(ail) | ((uint32_tt)f2bf(aih) << 16);
    }
}

// ---------------- layer-2 fused aggregate + bias + relu + store --------------
// Y [n][48 dwords]: 0-15 Yr, 16-31 Yin, 32-47 lin (bf16 pairs).
// Two waves per node, wave-level range split (same safe pattern as agg_bf16).
// Within a wave: lane-clamped address + single cndmask on coefficient
// (R11-verified clean codegen; NO half-wave metadata selects — R6/R12).
__global__ __launch_bounds__(256) void agg_out(
    const uint32_tt* __restrict__ Y, const int* __restrict__ off,
    const uint2* __restrict__ edat, const float* __restrict__ cb,
    const float* __restrict__ lb, float* __restrict__ out, int n) {
    __shared__ float part[2][2][64];
    int wave = threadIdx.x >> 6;
    int lane = threadIdx.x & 63;
    int pair = wave >> 1, half = wave & 1;
    int node = __builtin_amdgcn_readfirstlane(blockIdx.x * 2 + pair);
    int lc = (lane < 32) ? lane : 31;        // clamped lane offset
    int usei = (lane >> 4) & 1;              // 0: cr, 1: ci
    float alo = 0.f, ahi = 0.f;
    int eb = __builtin_amdgcn_readfirstlane(off[node]);
    int ee = __builtin_amdgcn_readfirstlane(off[node + 1]);
    int nbat = (ee - eb) >> 3;
    int b0 = (nbat + 1) >> 1;
    int e0 = half ? eb + b0 * 8 : eb;
    int e1 = half ? ee : eb + b0 * 8;

    if (e0 < e1) {
        uint2 mn[8];
        int sc[8]; float crc[8], cic[8];
        uint32_tt wc[8];
        {
            uint2 m0[8];
#pragma unroll
            for (int j = 0; j < 8; ++j) m0[j] = edat[e0 + j];
#pragma unroll
            for (int j = 0; j < 8; ++j) {
                sc[j] = __builtin_amdgcn_readfirstlane((int)m0[j].x);
                int pk = __builtin_amdgcn_readfirstlane((int)m0[j].y);
                crc[j] = bf2f((unsigned)pk & 0xffffu);
                cic[j] = bf2f((unsigned)pk >> 16);
            }
            int nb = (e0 + 8 < e1) ? e0 + 8 : e0;
#pragma unroll
            for (int j = 0; j < 8; ++j) mn[j] = edat[nb + j];
#pragma unroll
            for (int j = 0; j < 8; ++j) wc[j] = Y[(size_t)sc[j] * 48 + lc];
        }
        for (int e = e0;; e += 8) {
            bool more = (e + 8 < e1);
            int sn[8]; float crn[8], cin_[8]; uint32_tt wn[8];
            if (more) {
#pragma unroll
                for (int j = 0; j < 8; ++j) {
                    sn[j] = __builtin_amdgcn_readfirstlane((int)mn[j].x);
                    int pk = __builtin_amdgcn_readfirstlane((int)mn[j].y);
                    crn[j] = bf2f((unsigned)pk & 0xffffu);
                    cin_[j] = bf2f((unsigned)pk >> 16);
                }
                int nb = (e + 16 < e1) ? e + 16 : e + 8;
#pragma unroll
                for (int j = 0; j < 8; ++j) mn[j] = edat[nb + j];
#pragma unroll
                for (int j = 0; j < 8; ++j) wn[j] = Y[(size_t)sn[j] * 48 + lc];
            }
#pragma unroll
            for (int j = 0; j < 8; ++j) {
                float c = usei ? cic[j] : crc[j];
                float lo = bf2f(wc[j] & 0xffffu), hi = bf2f(wc[j] >> 16);
                alo += c * lo; ahi += c * hi;
            }
            if (!more) break;
#pragma unroll
            for (int j = 0; j < 8; ++j) {
                sc[j] = sn[j]; crc[j] = crn[j]; cic[j] = cin_[j]; wc[j] = wn[j];
            }
        }
    }
    if (half) {
        part[pair][0][lane] = alo;
        part[pair][1][lane] = ahi;
    }
    __syncthreads();
    if (!half) {
        alo += part[pair][0][lane];
        ahi += part[pair][1][lane];
        alo += __shfl_xor(alo, 16);
        ahi += __shfl_xor(ahi, 16);
        if (lane < 16) {
            uint32_tt lin = Y[(size_t)node * 48 + 32 + lane];
            int c0 = 2 * lane, c1 = 2 * lane + 1;
            float v0 = alo + bf2f(lin & 0xffffu) + cb[c0] + lb[c0];
            float v1 = ahi + bf2f(lin >> 16) + cb[c1] + lb[c1];
            float2 r;
            r.x = v0 > 0.f ? v0 : 0.f;
            r.y = v1 > 0.f ? v1 : 0.f;
            ((float2*)out)[(size_t)node * 16 + lane] = r;
        }
    }
}

// ---------------- bf16 MFMA GEMM (layer 0) -----------------------------------
template <int CINP, int COUT, int BM, int WM, int WN, int MT, int NT,
          bool OUT_BF16, bool RAW, int PARTS>
__global__ __launch_bounds__(256) void gemm_mfma(
    const unsigned short* __restrict__ A0, const unsigned short* __restrict__ A1,
    const unsigned short* __restrict__ A2, const unsigned short* __restrict__ BT,
    const float* __restrict__ cb, const float* __restrict__ lb,
    void* __restrict__ outv, int n) {
    constexpr int PK = 40;
    constexpr int KTOT = PARTS * CINP;
    constexpr int NCH = KTOT / 32;
    constexpr int CPP = CINP / 32;
    __shared__ unsigned short sA[BM][PK];
    __shared__ unsigned short sB[COUT][PK];

    int t = threadIdx.x;
    int lane = t & 63, wave = t >> 6;
    int wm = wave / WN, wn = wave % WN;
    int ml = lane & 15, kh = lane >> 4;
    int node0 = blockIdx.x * BM;

    const unsigned short* Asrc[3] = {A0, A1, A2};

    f32x4 acc[MT][NT];
#pragma unroll
    for (int mt = 0; mt < MT; ++mt)
#pragma unroll
        for (int nt = 0; nt < NT; ++nt) acc[mt][nt] = (f32x4){0.f, 0.f, 0.f, 0.f};

    for (int c = 0; c < NCH; ++c) {
        int part = (PARTS == 1) ? 0 : (c / CPP);
        int kk = (c - part * CPP) * 32;
        const unsigned short* __restrict__ Ap = Asrc[part];
        __syncthreads();
#pragma unroll
        for (int i = t; i < BM * 4; i += 256) {
            int r = i >> 2, q = i & 3;
            int node = node0 + r;
            if (node >= n) node = n - 1;
            *(uint4*)&sA[r][q * 8] =
                *(const uint4*)(Ap + (size_t)node * CINP + kk + q * 8);
        }
#pragma unroll
        for (int i = t; i < COUT * 4; i += 256) {
            int r = i >> 2, q = i & 3;
            *(uint4*)&sB[r][q * 8] =
                *(const uint4*)(BT + (size_t)r * KTOT + c * 32 + q * 8);
        }
        __syncthreads();
        bf16x8 af[MT], bfr[NT];
#pragma unroll
        for (int mt = 0; mt < MT; ++mt)
            af[mt] = *(const bf16x8*)&sA[wm * (MT * 16) + mt * 16 + ml][kh * 8];
#pragma unroll
        for (int nt = 0; nt < NT; ++nt)
            bfr[nt] = *(const bf16x8*)&sB[wn * (NT * 16) + nt * 16 + ml][kh * 8];
#pragma unroll
        for (int mt = 0; mt < MT; ++mt)
#pragma unroll
            for (int nt = 0; nt < NT; ++nt)
                acc[mt][nt] = __builtin_amdgcn_mfma_f32_16x16x32_bf16(
                    af[mt], bfr[nt], acc[mt][nt], 0, 0, 0);
    }

    int row0 = kh * 4;
#pragma unroll
    for (int nt = 0; nt < NT; ++nt) {
        int col = wn * (NT * 16) + nt * 16 + ml;
        float bias = RAW ? 0.f : (cb[col] + lb[col]);
#pragma unroll
        for (int mt = 0; mt < MT; ++mt) {
#pragma unroll
            for (int r = 0; r < 4; ++r) {
                int node = node0 + wm * (MT * 16) + mt * 16 + row0 + r;
                if (node < n) {
                    float v = acc[mt][nt][r] + bias;
                    if (!RAW) v = v > 0.f ? v : 0.f;
                    if (OUT_BF16)
                        ((unsigned short*)outv)[(size_t)node * COUT + col] = f2bf(v);
                    else
                        ((float*)outv)[(size_t)node * COUT + col] = v;
                }
            }
        }
    }
}

// ---------------- fused layer-1 GEMM + Y projection --------------------------
// Stage 1: h2 = relu([aggR|aggI|h1] @ BT1^T + b1)  -> LDS (bf16, never global)
// Stage 2: Y  = h2 @ BT2^T  (96 cols; BT2 frags from global, 24.6KB L1-hot)
__global__ __launch_bounds__(256) void gemm_l1y(
    const unsigned short* __restrict__ A0, const unsigned short* __restrict__ A1,
    const unsigned short* __restrict__ A2, const unsigned short* __restrict__ BT,
    const unsigned short* __restrict__ BT2, const float* __restrict__ cb,
    const float* __restrict__ lb, unsigned short* __restrict__ Yout, int n) {
    constexpr int PK = 40;
    constexpr int PH = 136;   // h2 LDS stride (16B-aligned rows)
    __shared__ unsigned short sA[128][PK];
    __shared__ unsigned short sB[128][PK];
    __shared__ unsigned short sH[128][PH];

    int t = threadIdx.x;
    int lane = t & 63, wave = t >> 6;
    int wm = wave >> 1, wn = wave & 1;
    int ml = lane & 15, kh = lane >> 4;
    int node0 = blockIdx.x * 128;
    const unsigned short* Asrc[3] = {A0, A1, A2};

    f32x4 acc[4][4];
#pragma unroll
    for (int mt = 0; mt < 4; ++mt)
#pragma unroll
        for (int nt = 0; nt < 4; ++nt) acc[mt][nt] = (f32x4){0.f, 0.f, 0.f, 0.f};

    for (int c = 0; c < 12; ++c) {          // KTOT=384, chunks of 32
        int part = c >> 2;
        int kk = (c & 3) * 32;
        const unsigned short* __restrict__ Ap = Asrc[part];
        __syncthreads();
#pragma unroll
        for (int i = t; i < 512; i += 256) {
            int r = i >> 2, q = i & 3;
            int node = node0 + r;
            if (node >= n) node = n - 1;
            *(uint4*)&sA[r][q * 8] =
                *(const uint4*)(Ap + (size_t)node * 128 + kk + q * 8);
        }
#pragma unroll
        for (int i = t; i < 512; i += 256) {
            int r = i >> 2, q = i & 3;
            *(uint4*)&sB[r][q * 8] =
                *(const uint4*)(BT + (size_t)r * 384 + c * 32 + q * 8);
        }
        __syncthreads();
        bf16x8 af[4], bfr[4];
#pragma unroll
        for (int mt = 0; mt < 4; ++mt)
            af[mt] = *(const bf16x8*)&sA[wm * 64 + mt * 16 + ml][kh * 8];
#pragma unroll
        for (int nt = 0; nt < 4; ++nt)
            bfr[nt] = *(const bf16x8*)&sB[wn * 64 + nt * 16 + ml][kh * 8];
#pragma unroll
        for (int mt = 0; mt < 4; ++mt)
#pragma unroll
            for (int nt = 0; nt < 4; ++nt)
                acc[mt][nt] = __builtin_amdgcn_mfma_f32_16x16x32_bf16(
                    af[mt], bfr[nt], acc[mt][nt], 0, 0, 0);
    }

    // epilogue 1: bias + relu -> bf16 -> sH[node][col]  (h2 stays on-chip)
    int row0 = kh * 4;
#pragma unroll
    for (int nt = 0; nt < 4; ++nt) {
        int col = wn * 64 + nt * 16 + ml;
        float bias = cb[col] + lb[col];
#pragma unroll
        for (int mt = 0; mt < 4; ++mt) {
#pragma unroll
            for (int r = 0; r < 4; ++r) {
                int nl = wm * 64 + mt * 16 + row0 + r;
                float v = acc[mt][nt][r] + bias;
                sH[nl][col] = f2bf(v > 0.f ? v : 0.f);
            }
        }
    }
    __syncthreads();

    // stage 2: Y[node][ycol] = sum_k h2[node][k] * BT2[ycol][k]
    f32x4 acc2[4][3];
#pragma unroll
    for (int mt = 0; mt < 4; ++mt)
#pragma unroll
        for (int nt = 0; nt < 3; ++nt) acc2[mt][nt] = (f32x4){0.f, 0.f, 0.f, 0.f};
    for (int c2 = 0; c2 < 4; ++c2) {
        bf16x8 af[4], bfr[3];
#pragma unroll
        for (int mt = 0; mt < 4; ++mt)
            af[mt] = *(const bf16x8*)&sH[wm * 64 + mt * 16 + ml][c2 * 32 + kh * 8];
#pragma unroll
        for (int nt = 0; nt < 3; ++nt) {
            int ycol = wn * 48 + nt * 16 + ml;
            bfr[nt] = *(const bf16x8*)(BT2 + (size_t)ycol * 128 + c2 * 32 + kh * 8);
        }
#pragma unroll
        for (int mt = 0; mt < 4; ++mt)
#pragma unroll
            for (int nt = 0; nt < 3; ++nt)
                acc2[mt][nt] = __builtin_amdgcn_mfma_f32_16x16x32_bf16(
                    af[mt], bfr[nt], acc2[mt][nt], 0, 0, 0);
    }
#pragma unroll
    for (int nt = 0; nt < 3; ++nt) {
        int ycol = wn * 48 + nt * 16 + ml;
#pragma unroll
        for (int mt = 0; mt < 4; ++mt) {
#pragma unroll
            for (int r = 0; r < 4; ++r) {
                int node = node0 + wm * 64 + mt * 16 + row0 + r;
                if (node < n)
                    Yout[(size_t)node * 96 + ycol] = f2bf(acc2[mt][nt][r]);
            }
        }
    }
}

// ---------------- launch ----------------

extern "C" void kernel_launch(void* const* d_in, const int* in_sizes, int n_in,
                              void* d_out, int out_size, void* d_ws, size_t ws_size,
                              hipStream_t stream) {
    const float* x0  = (const float*)d_in[0];
    const int*   ei  = (const int*)d_in[1];
    const float* wgt = (const float*)d_in[2];
    const float* sim = (const float*)d_in[3];
    const float *wr[3], *wi[3], *cb[3], *lw[3], *lb[3];
    for (int l = 0; l < 3; ++l) {
        wr[l] = (const float*)d_in[4 + 5 * l];
        wi[l] = (const float*)d_in[5 + 5 * l];
        cb[l] = (const float*)d_in[6 + 5 * l];
        lw[l] = (const float*)d_in[7 + 5 * l];
        lb[l] = (const float*)d_in[8 + 5 * l];
    }

    char* p = (char*)d_ws;
    auto alloc = [&](size_t bytes) -> void* {
        void* r = p;
        p += (bytes + 255) & ~(size_t)255;
        return r;
    };
    int*   off  = (int*)alloc((N_NODES + 1) * 4);
    int*   cnt  = (int*)alloc(N_NODES * 4);
    int*   bsum = (int*)alloc(256);
    int*   rank = (int*)alloc((size_t)N_EDGES * 4);
    uint2* edat = (uint2*)alloc((size_t)E_PAD_MAX * 8);
    unsigned short* xb    = (unsigned short*)alloc((size_t)N_NODES * 96 * 2);
    unsigned short* aggRb = (unsigned short*)alloc((size_t)N_NODES * 128 * 2);
    unsigned short* aggIb = (unsigned short*)alloc((size_t)N_NODES * 128 * 2);
    unsigned short* h1b   = (unsigned short*)alloc((size_t)N_NODES * 128 * 2);
    unsigned short* Yb    = (unsigned short*)alloc((size_t)N_NODES * 96 * 2);
    unsigned short* BT0   = (unsigned short*)alloc((size_t)128 * 288 * 2);
    unsigned short* BT1   = (unsigned short*)alloc((size_t)128 * 384 * 2);
    unsigned short* BT2   = (unsigned short*)alloc((size_t)96 * 128 * 2);
    float* outp = (float*)d_out;

    // merged prep FIRST (also zeroes cnt + edat; depends on nothing)
    {
        int total = N_NODES * 96 + 128 * 288 + 128 * 384 + 96 * 128;
        prep_kernel<<<(total + 255) / 256, 256, 0, stream>>>(
            x0, xb, wr[0], wi[0], lw[0], BT0, wr[1], wi[1], lw[1], BT1,
            wr[2], wi[2], lw[2], BT2, cnt, edat, N_NODES);
    }
    // CSR build: hist saves per-edge rank -> scatter is atomic-free
    hist_kernel<<<(N_EDGES + 255) / 256, 256, 0, stream>>>(ei, cnt, rank, N_EDGES);
    int nb = (N_NODES + 1023) / 1024;
    scan1<<<nb, 256, 0, stream>>>(cnt, off, bsum, N_NODES);
    scan3<<<(N_NODES + 1 + 255) / 256, 256, 0, stream>>>(off, bsum, N_NODES, nb);
    scatter_kernel<<<(N_EDGES + 255) / 256, 256, 0, stream>>>(ei, wgt, sim, off, rank,
                                                              edat, N_EDGES);

    int agrid = N_NODES / 2;   // 2 nodes per block (N even)

    // layer 0: xb [N,96] -> h1b [N,128]
    agg_bf16<48><<<agrid, 256, 0, stream>>>((const uint32_tt*)xb, off, edat,
                                            (uint32_tt*)aggRb, (uint32_tt*)aggIb, N_NODES);
    gemm_mfma<96, 128, 128, 2, 2, 4, 4, true, false, 3>
        <<<(N_NODES + 127) / 128, 256, 0, stream>>>(aggRb, aggIb, xb, BT0, cb[0], lb[0],
                                                    h1b, N_NODES);
    // layer 1 + Y projection fused: h1b -> (h2 in LDS) -> Yb [N,96]
    agg_bf16<64><<<agrid, 256, 0, stream>>>((const uint32_tt*)h1b, off, edat,
                                            (uint32_tt*)aggRb, (uint32_tt*)aggIb, N_NODES);
    gemm_l1y<<<(N_NODES + 127) / 128, 256, 0, stream>>>(aggRb, aggIb, h1b, BT1, BT2,
                                                        cb[1], lb[1], Yb, N_NODES);
    // layer 2: fused aggregate + bias + relu
    agg_out<<<agrid, 256, 0, stream>>>((const uint32_tt*)Yb, off, edat, cb[2], lb[2],
                                       outp, N_NODES);
}

// Round 15
// 256.704 us; speedup vs baseline: 1.1865x; 1.1865x over previous
//
#include <hip/hip_runtime.h>

#define N_NODES 50000
#define N_EDGES 600000
#define E_PAD_MAX (N_EDGES + N_NODES * 7)   // padded edge capacity

using bf16x8 = __attribute__((ext_vector_type(8))) short;
using f32x4  = __attribute__((ext_vector_type(4))) float;
typedef unsigned int uint32_tt;

__device__ __forceinline__ unsigned short f2bf(float f) {
    union { float f; unsigned int u; } v; v.f = f;
    unsigned int u = v.u;
    return (unsigned short)((u + 0x7fffu + ((u >> 16) & 1u)) >> 16);  // RNE
}
__device__ __forceinline__ float bf2f(unsigned int h16) {
    union { unsigned int u; float f; } v; v.u = h16 << 16;
    return v.f;
}

// ---------------- merged prep (runs FIRST, depends on nothing) ---------------
__global__ void prep_kernel(
    const float* __restrict__ x0, unsigned short* __restrict__ xb,
    const float* __restrict__ wr0, const float* __restrict__ wi0,
    const float* __restrict__ lw0, unsigned short* __restrict__ BT0,
    const float* __restrict__ wr1, const float* __restrict__ wi1,
    const float* __restrict__ lw1, unsigned short* __restrict__ BT1,
    const float* __restrict__ wr2, const float* __restrict__ wi2,
    const float* __restrict__ lw2, unsigned short* __restrict__ BT2,
    int* __restrict__ cnt, uint2* __restrict__ edat, int n) {
    int tid = blockIdx.x * 256 + threadIdx.x;
    int nth = gridDim.x * 256;
    for (int i = tid; i < N_NODES; i += nth) cnt[i] = 0;
    uint2 z; z.x = 0u; z.y = 0u;
    for (int i = tid; i < E_PAD_MAX; i += nth) edat[i] = z;

    int i = tid;
    int nconv = n * 96;
    if (i < nconv) {
        int r = i / 96, c = i - r * 96;
        xb[i] = (c < 75) ? f2bf(x0[r * 75 + c]) : (unsigned short)0;
        return;
    }
    i -= nconv;
    if (i < 128 * 288) {   // BT0: CIN=75 CINP=96 COUT=128
        int nn = i / 288, k = i - nn * 288;
        int part = k / 96, kk = k - part * 96;
        float v = 0.f;
        if (kk < 75) {
            if (part == 0)      v = wr0[kk * 128 + nn];
            else if (part == 1) v = -wi0[kk * 128 + nn];
            else                v = lw0[nn * 75 + kk];
        }
        BT0[i] = f2bf(v);
        return;
    }
    i -= 128 * 288;
    if (i < 128 * 384) {   // BT1: CIN=CINP=128 COUT=128
        int nn = i / 384, k = i - nn * 384;
        int part = k >> 7, kk = k & 127;
        float v;
        if (part == 0)      v = wr1[kk * 128 + nn];
        else if (part == 1) v = -wi1[kk * 128 + nn];
        else                v = lw1[nn * 128 + kk];
        BT1[i] = f2bf(v);
        return;
    }
    i -= 128 * 384;
    if (i < 96 * 128) {    // BT2 (Y-projection): [96 rows][128 k] = [wr2|-wi2|lw2^T]
        int nn = i >> 7, k = i & 127;
        float v;
        if (nn < 32)      v = wr2[k * 32 + nn];
        else if (nn < 64) v = -wi2[k * 32 + (nn - 32)];
        else              v = lw2[(nn - 64) * 128 + k];
        BT2[i] = f2bf(v);
    }
}

// ---------------- CSR build (degrees padded to multiple of 8) ----------------

__global__ void hist_kernel(const int* __restrict__ ei, int* __restrict__ cnt,
                            int* __restrict__ rank, int E) {
    int e = blockIdx.x * 256 + threadIdx.x;
    if (e < E) rank[e] = atomicAdd(&cnt[ei[E + e]], 1);
}

__global__ void scan1(const int* __restrict__ deg, int* __restrict__ out,
                      int* __restrict__ bsum, int n) {
    __shared__ int s[256];
    int t = threadIdx.x;
    int base = blockIdx.x * 1024 + t * 4;
    int v0 = (base + 0 < n) ? ((deg[base + 0] + 7) & ~7) : 0;
    int v1 = (base + 1 < n) ? ((deg[base + 1] + 7) & ~7) : 0;
    int v2 = (base + 2 < n) ? ((deg[base + 2] + 7) & ~7) : 0;
    int v3 = (base + 3 < n) ? ((deg[base + 3] + 7) & ~7) : 0;
    int tsum = v0 + v1 + v2 + v3;
    s[t] = tsum;
    __syncthreads();
    for (int off = 1; off < 256; off <<= 1) {
        int tmp = (t >= off) ? s[t - off] : 0;
        __syncthreads();
        s[t] += tmp;
        __syncthreads();
    }
    int excl = s[t] - tsum;
    if (base + 0 < n) out[base + 0] = excl;
    if (base + 1 < n) out[base + 1] = excl + v0;
    if (base + 2 < n) out[base + 2] = excl + v0 + v1;
    if (base + 3 < n) out[base + 3] = excl + v0 + v1 + v2;
    if (t == 255) bsum[blockIdx.x] = s[255];
}

// scan3 with scan2 folded in (thread 0 sums <=49 L2-hot block totals)
__global__ void scan3(int* __restrict__ off, const int* __restrict__ bsum,
                      int n, int nb) {
    __shared__ int sp;
    int b = blockIdx.x, t = threadIdx.x;
    int seg = b >> 2;
    if (t == 0) {
        int acc = 0;
        for (int k = 0; k < seg; ++k) acc += bsum[k];
        sp = acc;
    }
    __syncthreads();
    int i = b * 256 + t;
    if (i < n) off[i] += sp;
    if (i == n) {
        int tot = sp;
        for (int k = seg; k < nb; ++k) tot += bsum[k];
        off[n] = tot;
    }
}

// atomic-free scatter: p = off[d] + rank[e]
__global__ void scatter_kernel(const int* __restrict__ ei, const float* __restrict__ w,
                               const float* __restrict__ sim, const int* __restrict__ off,
                               const int* __restrict__ rank, uint2* __restrict__ edat,
                               int E) {
    int e = blockIdx.x * 256 + threadIdx.x;
    if (e >= E) return;
    int s = ei[e], d = ei[E + e];
    int p = off[d] + rank[e];
    float wt = w[e];
    uint2 m;
    m.x = (unsigned)s;
    m.y = (uint32_tt)f2bf(wt * sim[2 * e]) |
          ((uint32_tt)f2bf(wt * sim[2 * e + 1]) << 16);
    edat[p] = m;
}

// ---------------- aggregation: one wave per node, pipelined gathers ----------
// R13-verified floor for this decomposition: R8 deeper pipelining was neutral,
// R14 two-waves-per-node regressed (per-wave preamble latency dominates).
template <int CU2>  // uint32s per feature row (= CINP/2)
__global__ __launch_bounds__(256) void agg_bf16(
    const uint32_tt* __restrict__ x, const int* __restrict__ off,
    const uint2* __restrict__ edat, uint32_tt* __restrict__ aggR,
    uint32_tt* __restrict__ aggI, int n) {
    int wave = threadIdx.x >> 6;
    int lane = threadIdx.x & 63;
    int node = __builtin_amdgcn_readfirstlane(blockIdx.x * 4 + wave);
    if (node >= n) return;
    int lc = (CU2 == 64) ? lane : (lane < CU2 ? lane : CU2 - 1);  // clamped lane
    float arl = 0.f, arh = 0.f, ail = 0.f, aih = 0.f;
    int e0 = __builtin_amdgcn_readfirstlane(off[node]);
    int e1 = __builtin_amdgcn_readfirstlane(off[node + 1]);

    if (e0 < e1) {
        uint2 mn[8];
        int sc[8]; float crc[8], cic[8];
        uint32_tt wc[8];
        {
            uint2 m0[8];
#pragma unroll
            for (int j = 0; j < 8; ++j) m0[j] = edat[e0 + j];
#pragma unroll
            for (int j = 0; j < 8; ++j) {
                sc[j] = __builtin_amdgcn_readfirstlane((int)m0[j].x);
                int pk = __builtin_amdgcn_readfirstlane((int)m0[j].y);
                crc[j] = bf2f((unsigned)pk & 0xffffu);
                cic[j] = bf2f((unsigned)pk >> 16);
            }
            int nb = (e0 + 8 < e1) ? e0 + 8 : e0;
#pragma unroll
            for (int j = 0; j < 8; ++j) mn[j] = edat[nb + j];
#pragma unroll
            for (int j = 0; j < 8; ++j) wc[j] = x[(size_t)sc[j] * CU2 + lc];
        }
        for (int e = e0;; e += 8) {
            bool more = (e + 8 < e1);      // wave-uniform
            int sn[8]; float crn[8], cin_[8]; uint32_tt wn[8];
            if (more) {
#pragma unroll
                for (int j = 0; j < 8; ++j) {
                    sn[j] = __builtin_amdgcn_readfirstlane((int)mn[j].x);
                    int pk = __builtin_amdgcn_readfirstlane((int)mn[j].y);
                    crn[j] = bf2f((unsigned)pk & 0xffffu);
                    cin_[j] = bf2f((unsigned)pk >> 16);
                }
                int nb = (e + 16 < e1) ? e + 16 : e + 8;
#pragma unroll
                for (int j = 0; j < 8; ++j) mn[j] = edat[nb + j];
#pragma unroll
                for (int j = 0; j < 8; ++j) wn[j] = x[(size_t)sn[j] * CU2 + lc];
            }
#pragma unroll
            for (int j = 0; j < 8; ++j) {
                float lo = bf2f(wc[j] & 0xffffu), hi = bf2f(wc[j] >> 16);
                arl += crc[j] * lo; arh += crc[j] * hi;
                ail += cic[j] * lo; aih += cic[j] * hi;
            }
            if (!more) break;
#pragma unroll
            for (int j = 0; j < 8; ++j) {
                sc[j] = sn[j]; crc[j] = crn[j]; cic[j] = cin_[j]; wc[j] = wn[j];
            }
        }
    }
    if (lane < CU2) {
        aggR[(size_t)node * CU2 + lane] = (uint32_tt)f2bf(arl) | ((uint32_tt)f2bf(arh) << 16);
        aggI[(size_t)node * CU2 + lane] = (uint32_tt)f2bf(ail) | ((uint32_tt)f2bf(aih) << 16);
    }
}

// ---------------- layer-2 fused aggregate + bias + relu + store --------------
// Y [n][48 dwords]: 0-15 Yr, 16-31 Yin, 32-47 lin (bf16 pairs).
// R11-verified structure (clean codegen): lane-clamped address, single
// cndmask on coefficient, lanes 32-63 duplicate-discard.
// DO NOT reintroduce lane-dependent selects across private arrays (R6/R12
// demotion: LDS_Block 16K, VGPR 16, 7e6 bank conflicts).
__global__ __launch_bounds__(256) void agg_out(
    const uint32_tt* __restrict__ Y, const int* __restrict__ off,
    const uint2* __restrict__ edat, const float* __restrict__ cb,
    const float* __restrict__ lb, float* __restrict__ out, int n) {
    int wave = threadIdx.x >> 6;
    int lane = threadIdx.x & 63;
    int node = __builtin_amdgcn_readfirstlane(blockIdx.x * 4 + wave);
    if (node >= n) return;
    int lc = (lane < 32) ? lane : 31;        // clamped lane offset
    int usei = (lane >> 4) & 1;              // 0: cr, 1: ci
    float alo = 0.f, ahi = 0.f;
    int e0 = __builtin_amdgcn_readfirstlane(off[node]);
    int e1 = __builtin_amdgcn_readfirstlane(off[node + 1]);

    if (e0 < e1) {
        uint2 mn[8];
        int sc[8]; float crc[8], cic[8];
        uint32_tt wc[8];
        {
            uint2 m0[8];
#pragma unroll
            for (int j = 0; j < 8; ++j) m0[j] = edat[e0 + j];
#pragma unroll
            for (int j = 0; j < 8; ++j) {
                sc[j] = __builtin_amdgcn_readfirstlane((int)m0[j].x);
                int pk = __builtin_amdgcn_readfirstlane((int)m0[j].y);
                crc[j] = bf2f((unsigned)pk & 0xffffu);
                cic[j] = bf2f((unsigned)pk >> 16);
            }
            int nb = (e0 + 8 < e1) ? e0 + 8 : e0;
#pragma unroll
            for (int j = 0; j < 8; ++j) mn[j] = edat[nb + j];
#pragma unroll
            for (int j = 0; j < 8; ++j) wc[j] = Y[(size_t)sc[j] * 48 + lc];
        }
        for (int e = e0;; e += 8) {
            bool more = (e + 8 < e1);
            int sn[8]; float crn[8], cin_[8]; uint32_tt wn[8];
            if (more) {
#pragma unroll
                for (int j = 0; j < 8; ++j) {
                    sn[j] = __builtin_amdgcn_readfirstlane((int)mn[j].x);
                    int pk = __builtin_amdgcn_readfirstlane((int)mn[j].y);
                    crn[j] = bf2f((unsigned)pk & 0xffffu);
                    cin_[j] = bf2f((unsigned)pk >> 16);
                }
                int nb = (e + 16 < e1) ? e + 16 : e + 8;
#pragma unroll
                for (int j = 0; j < 8; ++j) mn[j] = edat[nb + j];
#pragma unroll
                for (int j = 0; j < 8; ++j) wn[j] = Y[(size_t)sn[j] * 48 + lc];
            }
#pragma unroll
            for (int j = 0; j < 8; ++j) {
                float c = usei ? cic[j] : crc[j];
                float lo = bf2f(wc[j] & 0xffffu), hi = bf2f(wc[j] >> 16);
                alo += c * lo; ahi += c * hi;
            }
            if (!more) break;
#pragma unroll
            for (int j = 0; j < 8; ++j) {
                sc[j] = sn[j]; crc[j] = crn[j]; cic[j] = cin_[j]; wc[j] = wn[j];
            }
        }
    }
    alo += __shfl_xor(alo, 16);
    ahi += __shfl_xor(ahi, 16);
    if (lane < 16) {
        uint32_tt lin = Y[(size_t)node * 48 + 32 + lane];
        int c0 = 2 * lane, c1 = 2 * lane + 1;
        float v0 = alo + bf2f(lin & 0xffffu) + cb[c0] + lb[c0];
        float v1 = ahi + bf2f(lin >> 16) + cb[c1] + lb[c1];
        float2 r;
        r.x = v0 > 0.f ? v0 : 0.f;
        r.y = v1 > 0.f ? v1 : 0.f;
        ((float2*)out)[(size_t)node * 16 + lane] = r;
    }
}

// ---------------- bf16 MFMA GEMM (layer 0) -----------------------------------
template <int CINP, int COUT, int BM, int WM, int WN, int MT, int NT,
          bool OUT_BF16, bool RAW, int PARTS>
__global__ __launch_bounds__(256) void gemm_mfma(
    const unsigned short* __restrict__ A0, const unsigned short* __restrict__ A1,
    const unsigned short* __restrict__ A2, const unsigned short* __restrict__ BT,
    const float* __restrict__ cb, const float* __restrict__ lb,
    void* __restrict__ outv, int n) {
    constexpr int PK = 40;
    constexpr int KTOT = PARTS * CINP;
    constexpr int NCH = KTOT / 32;
    constexpr int CPP = CINP / 32;
    __shared__ unsigned short sA[BM][PK];
    __shared__ unsigned short sB[COUT][PK];

    int t = threadIdx.x;
    int lane = t & 63, wave = t >> 6;
    int wm = wave / WN, wn = wave % WN;
    int ml = lane & 15, kh = lane >> 4;
    int node0 = blockIdx.x * BM;

    const unsigned short* Asrc[3] = {A0, A1, A2};

    f32x4 acc[MT][NT];
#pragma unroll
    for (int mt = 0; mt < MT; ++mt)
#pragma unroll
        for (int nt = 0; nt < NT; ++nt) acc[mt][nt] = (f32x4){0.f, 0.f, 0.f, 0.f};

    for (int c = 0; c < NCH; ++c) {
        int part = (PARTS == 1) ? 0 : (c / CPP);
        int kk = (c - part * CPP) * 32;
        const unsigned short* __restrict__ Ap = Asrc[part];
        __syncthreads();
#pragma unroll
        for (int i = t; i < BM * 4; i += 256) {
            int r = i >> 2, q = i & 3;
            int node = node0 + r;
            if (node >= n) node = n - 1;
            *(uint4*)&sA[r][q * 8] =
                *(const uint4*)(Ap + (size_t)node * CINP + kk + q * 8);
        }
#pragma unroll
        for (int i = t; i < COUT * 4; i += 256) {
            int r = i >> 2, q = i & 3;
            *(uint4*)&sB[r][q * 8] =
                *(const uint4*)(BT + (size_t)r * KTOT + c * 32 + q * 8);
        }
        __syncthreads();
        bf16x8 af[MT], bfr[NT];
#pragma unroll
        for (int mt = 0; mt < MT; ++mt)
            af[mt] = *(const bf16x8*)&sA[wm * (MT * 16) + mt * 16 + ml][kh * 8];
#pragma unroll
        for (int nt = 0; nt < NT; ++nt)
            bfr[nt] = *(const bf16x8*)&sB[wn * (NT * 16) + nt * 16 + ml][kh * 8];
#pragma unroll
        for (int mt = 0; mt < MT; ++mt)
#pragma unroll
            for (int nt = 0; nt < NT; ++nt)
                acc[mt][nt] = __builtin_amdgcn_mfma_f32_16x16x32_bf16(
                    af[mt], bfr[nt], acc[mt][nt], 0, 0, 0);
    }

    int row0 = kh * 4;
#pragma unroll
    for (int nt = 0; nt < NT; ++nt) {
        int col = wn * (NT * 16) + nt * 16 + ml;
        float bias = RAW ? 0.f : (cb[col] + lb[col]);
#pragma unroll
        for (int mt = 0; mt < MT; ++mt) {
#pragma unroll
            for (int r = 0; r < 4; ++r) {
                int node = node0 + wm * (MT * 16) + mt * 16 + row0 + r;
                if (node < n) {
                    float v = acc[mt][nt][r] + bias;
                    if (!RAW) v = v > 0.f ? v : 0.f;
                    if (OUT_BF16)
                        ((unsigned short*)outv)[(size_t)node * COUT + col] = f2bf(v);
                    else
                        ((float*)outv)[(size_t)node * COUT + col] = v;
                }
            }
        }
    }
}

// ---------------- fused layer-1 GEMM + Y projection --------------------------
// Stage 1: h2 = relu([aggR|aggI|h1] @ BT1^T + b1)  -> LDS (bf16, never global)
// Stage 2: Y  = h2 @ BT2^T  (96 cols; BT2 frags from global, 24.6KB L1-hot)
__global__ __launch_bounds__(256) void gemm_l1y(
    const unsigned short* __restrict__ A0, const unsigned short* __restrict__ A1,
    const unsigned short* __restrict__ A2, const unsigned short* __restrict__ BT,
    const unsigned short* __restrict__ BT2, const float* __restrict__ cb,
    const float* __restrict__ lb, unsigned short* __restrict__ Yout, int n) {
    constexpr int PK = 40;
    constexpr int PH = 136;   // h2 LDS stride (16B-aligned rows)
    __shared__ unsigned short sA[128][PK];
    __shared__ unsigned short sB[128][PK];
    __shared__ unsigned short sH[128][PH];

    int t = threadIdx.x;
    int lane = t & 63, wave = t >> 6;
    int wm = wave >> 1, wn = wave & 1;
    int ml = lane & 15, kh = lane >> 4;
    int node0 = blockIdx.x * 128;
    const unsigned short* Asrc[3] = {A0, A1, A2};

    f32x4 acc[4][4];
#pragma unroll
    for (int mt = 0; mt < 4; ++mt)
#pragma unroll
        for (int nt = 0; nt < 4; ++nt) acc[mt][nt] = (f32x4){0.f, 0.f, 0.f, 0.f};

    for (int c = 0; c < 12; ++c) {          // KTOT=384, chunks of 32
        int part = c >> 2;
        int kk = (c & 3) * 32;
        const unsigned short* __restrict__ Ap = Asrc[part];
        __syncthreads();
#pragma unroll
        for (int i = t; i < 512; i += 256) {
            int r = i >> 2, q = i & 3;
            int node = node0 + r;
            if (node >= n) node = n - 1;
            *(uint4*)&sA[r][q * 8] =
                *(const uint4*)(Ap + (size_t)node * 128 + kk + q * 8);
        }
#pragma unroll
        for (int i = t; i < 512; i += 256) {
            int r = i >> 2, q = i & 3;
            *(uint4*)&sB[r][q * 8] =
                *(const uint4*)(BT + (size_t)r * 384 + c * 32 + q * 8);
        }
        __syncthreads();
        bf16x8 af[4], bfr[4];
#pragma unroll
        for (int mt = 0; mt < 4; ++mt)
            af[mt] = *(const bf16x8*)&sA[wm * 64 + mt * 16 + ml][kh * 8];
#pragma unroll
        for (int nt = 0; nt < 4; ++nt)
            bfr[nt] = *(const bf16x8*)&sB[wn * 64 + nt * 16 + ml][kh * 8];
#pragma unroll
        for (int mt = 0; mt < 4; ++mt)
#pragma unroll
            for (int nt = 0; nt < 4; ++nt)
                acc[mt][nt] = __builtin_amdgcn_mfma_f32_16x16x32_bf16(
                    af[mt], bfr[nt], acc[mt][nt], 0, 0, 0);
    }

    // epilogue 1: bias + relu -> bf16 -> sH[node][col]  (h2 stays on-chip)
    int row0 = kh * 4;
#pragma unroll
    for (int nt = 0; nt < 4; ++nt) {
        int col = wn * 64 + nt * 16 + ml;
        float bias = cb[col] + lb[col];
#pragma unroll
        for (int mt = 0; mt < 4; ++mt) {
#pragma unroll
            for (int r = 0; r < 4; ++r) {
                int nl = wm * 64 + mt * 16 + row0 + r;
                float v = acc[mt][nt][r] + bias;
                sH[nl][col] = f2bf(v > 0.f ? v : 0.f);
            }
        }
    }
    __syncthreads();

    // stage 2: Y[node][ycol] = sum_k h2[node][k] * BT2[ycol][k]
    f32x4 acc2[4][3];
#pragma unroll
    for (int mt = 0; mt < 4; ++mt)
#pragma unroll
        for (int nt = 0; nt < 3; ++nt) acc2[mt][nt] = (f32x4){0.f, 0.f, 0.f, 0.f};
    for (int c2 = 0; c2 < 4; ++c2) {
        bf16x8 af[4], bfr[3];
#pragma unroll
        for (int mt = 0; mt < 4; ++mt)
            af[mt] = *(const bf16x8*)&sH[wm * 64 + mt * 16 + ml][c2 * 32 + kh * 8];
#pragma unroll
        for (int nt = 0; nt < 3; ++nt) {
            int ycol = wn * 48 + nt * 16 + ml;
            bfr[nt] = *(const bf16x8*)(BT2 + (size_t)ycol * 128 + c2 * 32 + kh * 8);
        }
#pragma unroll
        for (int mt = 0; mt < 4; ++mt)
#pragma unroll
            for (int nt = 0; nt < 3; ++nt)
                acc2[mt][nt] = __builtin_amdgcn_mfma_f32_16x16x32_bf16(
                    af[mt], bfr[nt], acc2[mt][nt], 0, 0, 0);
    }
#pragma unroll
    for (int nt = 0; nt < 3; ++nt) {
        int ycol = wn * 48 + nt * 16 + ml;
#pragma unroll
        for (int mt = 0; mt < 4; ++mt) {
#pragma unroll
            for (int r = 0; r < 4; ++r) {
                int node = node0 + wm * 64 + mt * 16 + row0 + r;
                if (node < n)
                    Yout[(size_t)node * 96 + ycol] = f2bf(acc2[mt][nt][r]);
            }
        }
    }
}

// ---------------- launch ----------------

extern "C" void kernel_launch(void* const* d_in, const int* in_sizes, int n_in,
                              void* d_out, int out_size, void* d_ws, size_t ws_size,
                              hipStream_t stream) {
    const float* x0  = (const float*)d_in[0];
    const int*   ei  = (const int*)d_in[1];
    const float* wgt = (const float*)d_in[2];
    const float* sim = (const float*)d_in[3];
    const float *wr[3], *wi[3], *cb[3], *lw[3], *lb[3];
    for (int l = 0; l < 3; ++l) {
        wr[l] = (const float*)d_in[4 + 5 * l];
        wi[l] = (const float*)d_in[5 + 5 * l];
        cb[l] = (const float*)d_in[6 + 5 * l];
        lw[l] = (const float*)d_in[7 + 5 * l];
        lb[l] = (const float*)d_in[8 + 5 * l];
    }

    char* p = (char*)d_ws;
    auto alloc = [&](size_t bytes) -> void* {
        void* r = p;
        p += (bytes + 255) & ~(size_t)255;
        return r;
    };
    int*   off  = (int*)alloc((N_NODES + 1) * 4);
    int*   cnt  = (int*)alloc(N_NODES * 4);
    int*   bsum = (int*)alloc(256);
    int*   rank = (int*)alloc((size_t)N_EDGES * 4);
    uint2* edat = (uint2*)alloc((size_t)E_PAD_MAX * 8);
    unsigned short* xb    = (unsigned short*)alloc((size_t)N_NODES * 96 * 2);
    unsigned short* aggRb = (unsigned short*)alloc((size_t)N_NODES * 128 * 2);
    unsigned short* aggIb = (unsigned short*)alloc((size_t)N_NODES * 128 * 2);
    unsigned short* h1b   = (unsigned short*)alloc((size_t)N_NODES * 128 * 2);
    unsigned short* Yb    = (unsigned short*)alloc((size_t)N_NODES * 96 * 2);
    unsigned short* BT0   = (unsigned short*)alloc((size_t)128 * 288 * 2);
    unsigned short* BT1   = (unsigned short*)alloc((size_t)128 * 384 * 2);
    unsigned short* BT2   = (unsigned short*)alloc((size_t)96 * 128 * 2);
    float* outp = (float*)d_out;

    // merged prep FIRST (also zeroes cnt + edat; depends on nothing)
    {
        int total = N_NODES * 96 + 128 * 288 + 128 * 384 + 96 * 128;
        prep_kernel<<<(total + 255) / 256, 256, 0, stream>>>(
            x0, xb, wr[0], wi[0], lw[0], BT0, wr[1], wi[1], lw[1], BT1,
            wr[2], wi[2], lw[2], BT2, cnt, edat, N_NODES);
    }
    // CSR build: hist saves per-edge rank -> scatter is atomic-free
    hist_kernel<<<(N_EDGES + 255) / 256, 256, 0, stream>>>(ei, cnt, rank, N_EDGES);
    int nb = (N_NODES + 1023) / 1024;
    scan1<<<nb, 256, 0, stream>>>(cnt, off, bsum, N_NODES);
    scan3<<<(N_NODES + 1 + 255) / 256, 256, 0, stream>>>(off, bsum, N_NODES, nb);
    scatter_kernel<<<(N_EDGES + 255) / 256, 256, 0, stream>>>(ei, wgt, sim, off, rank,
                                                              edat, N_EDGES);

    int agrid = (N_NODES + 3) / 4;

    // layer 0: xb [N,96] -> h1b [N,128]
    agg_bf16<48><<<agrid, 256, 0, stream>>>((const uint32_tt*)xb, off, edat,
                                            (uint32_tt*)aggRb, (uint32_tt*)aggIb, N_NODES);
    gemm_mfma<96, 128, 128, 2, 2, 4, 4, true, false, 3>
        <<<(N_NODES + 127) / 128, 256, 0, stream>>>(aggRb, aggIb, xb, BT0, cb[0], lb[0],
                                                    h1b, N_NODES);
    // layer 1 + Y projection fused: h1b -> (h2 in LDS) -> Yb [N,96]
    agg_bf16<64><<<agrid, 256, 0, stream>>>((const uint32_tt*)h1b, off, edat,
                                            (uint32_tt*)aggRb, (uint32_tt*)aggIb, N_NODES);
    gemm_l1y<<<(N_NODES + 127) / 128, 256, 0, stream>>>(aggRb, aggIb, h1b, BT1, BT2,
                                                        cb[1], lb[1], Yb, N_NODES);
    // layer 2: fused aggregate + bias + relu
    agg_out<<<agrid, 256, 0, stream>>>((const uint32_tt*)Yb, off, edat, cb[2], lb[2],
                                       outp, N_NODES);
}